// Round 9
// baseline (233.267 us; speedup 1.0000x reference)
//
#include <hip/hip_runtime.h>
#include <math.h>

// Problem: B=64, R=20, L=1024, D=2048 fp32.  out[b,l] = max_r <region[b,r,:], word[b,l,:]>
// Memory-bound: 548 MB mandatory -> ~84us @ 6.6TB/s measured-achievable.
//
// Round-9 = round-8 + WORD PREFETCH one chunk ahead, in NAMED float4 regs.
//  - rounds 2/5/8 plateau at ~144us with three different stage schedules ->
//    stage drain is NOT the bottleneck; exposed per-chunk word latency is the
//    remaining suspect (~1000cy x 8 chunks, words loaded at point of use).
//  - rounds 6/7 "prefetch" attempts actually died of rule #20: float4 arrays
//    passed as pointers into lambdas -> scratch (round 7: 1.37 GB WRITE_SIZE).
//    This round uses ONLY named scalars + macros: no arrays, no pointers.
//  - per chunk: barrier (drains loads issued one full compute-phase earlier,
//    ~free) -> issue stage(c+1)+words(c+1) -> compute(c) with ZERO vmem waits.
//  - no min-waves launch bound (rounds 3/4: VGPR cap spills the 80-reg acc).
#define NREG  20
#define LWORDS 1024
#define DDIM  2048
#define DK    256                   // D-chunk: 20*256*4B = 20 KB per buffer
#define NCHUNK (DDIM / DK)          // 8
#define NWAVE 4
#define TPB   (NWAVE * 64)          // 256
#define WPW   4                     // words per wave
#define WORDS_PER_BLOCK (NWAVE * WPW)   // 16

// async global->LDS, 16B per lane; dst must be wave-uniform (HW adds lane*16)
__device__ __forceinline__ void gload_lds16(const float* src, float* dst) {
    __builtin_amdgcn_global_load_lds(
        (const __attribute__((address_space(1))) void*)src,
        (__attribute__((address_space(3))) void*)dst,
        16, 0, 0);
}

// DPP full-wave (64-lane) sum; result valid in lane 63.
template <int CTRL>
__device__ __forceinline__ float dpp_add_f32(float v) {
    int s = __builtin_amdgcn_update_dpp(0, __float_as_int(v), CTRL, 0xf, 0xf, true);
    return v + __int_as_float(s);
}
__device__ __forceinline__ float wave_sum64(float v) {
    v = dpp_add_f32<0x111>(v);  // row_shr:1
    v = dpp_add_f32<0x112>(v);  // row_shr:2
    v = dpp_add_f32<0x114>(v);  // row_shr:4
    v = dpp_add_f32<0x118>(v);  // row_shr:8
    v = dpp_add_f32<0x142>(v);  // row_bcast:15
    v = dpp_add_f32<0x143>(v);  // row_bcast:31 -> lane 63 = total
    return v;
}

// load 4 word float4s for chunk (c) into named vars v0..v3
#define WVLOAD(v0, v1, v2, v3, c)                                              \
    do {                                                                       \
        const float* wp_ = wordp + (size_t)(c) * DK;                           \
        v0 = *reinterpret_cast<const float4*>(wp_);                            \
        v1 = *reinterpret_cast<const float4*>(wp_ + DDIM);                     \
        v2 = *reinterpret_cast<const float4*>(wp_ + 2 * (size_t)DDIM);         \
        v3 = *reinterpret_cast<const float4*>(wp_ + 3 * (size_t)DDIM);         \
    } while (0)

// FMA chunk: acc[r][0..3] += region(lds buf) * {v0..v3}
#define COMPUTE(bufsel, v0, v1, v2, v3)                                        \
    do {                                                                       \
        const float* rbase_ = &reg_lds[bufsel][lane * 4];                      \
        _Pragma("unroll")                                                      \
        for (int r = 0; r < NREG; ++r) {                                       \
            const float4 rv = *reinterpret_cast<const float4*>(rbase_ + r * DK); \
            float a0 = acc[r][0], a1 = acc[r][1], a2 = acc[r][2], a3 = acc[r][3]; \
            a0 = fmaf(rv.x, v0.x, a0); a1 = fmaf(rv.x, v1.x, a1);              \
            a2 = fmaf(rv.x, v2.x, a2); a3 = fmaf(rv.x, v3.x, a3);              \
            a0 = fmaf(rv.y, v0.y, a0); a1 = fmaf(rv.y, v1.y, a1);              \
            a2 = fmaf(rv.y, v2.y, a2); a3 = fmaf(rv.y, v3.y, a3);              \
            a0 = fmaf(rv.z, v0.z, a0); a1 = fmaf(rv.z, v1.z, a1);              \
            a2 = fmaf(rv.z, v2.z, a2); a3 = fmaf(rv.z, v3.z, a3);              \
            a0 = fmaf(rv.w, v0.w, a0); a1 = fmaf(rv.w, v1.w, a1);              \
            a2 = fmaf(rv.w, v2.w, a2); a3 = fmaf(rv.w, v3.w, a3);              \
            acc[r][0] = a0; acc[r][1] = a1; acc[r][2] = a2; acc[r][3] = a3;    \
        }                                                                      \
    } while (0)

__global__ __launch_bounds__(TPB)
void score_max_kernel(const float* __restrict__ in0,   // (B*20, D) regions
                      const float* __restrict__ in1,   // (B, L, D) words
                      float* __restrict__ out) {       // (B, 1, L)
    __shared__ float reg_lds[2][NREG * DK];            // 40 KB double buffer

    const int bid  = blockIdx.x;
    // bid = t*64 + b: batch b always lands on XCD (b%8) -> regions L2-resident.
    const int b    = bid & 63;
    const int t    = bid >> 6;
    const int tid  = threadIdx.x;
    const int wave = tid >> 6;
    const int lane = tid & 63;
    const int l0   = t * WORDS_PER_BLOCK + wave * WPW;

    const float* regbase = in0 + (size_t)b * NREG * DDIM;
    const float* wordp   = in1 + ((size_t)b * LWORDS + l0) * DDIM + lane * 4;

    // stage regions[0..19][c*DK .. +DK) into reg_lds[bufsel] (async, 5 rows/wave)
    auto stage = [&](int bufsel, int c) {
        #pragma unroll
        for (int i = 0; i < NREG / NWAVE; ++i) {        // 5 rows per wave
            const int r = i * NWAVE + wave;              // wave-uniform row
            gload_lds16(regbase + (size_t)r * DDIM + c * DK + lane * 4,
                        &reg_lds[bufsel][r * DK]);
        }
    };

    float acc[NREG][WPW];
    #pragma unroll
    for (int r = 0; r < NREG; ++r)
        #pragma unroll
        for (int w = 0; w < WPW; ++w) acc[r][w] = 0.0f;

    float4 wa0, wa1, wa2, wa3;   // words, even chunks
    float4 wb0, wb1, wb2, wb3;   // words, odd chunks

    // prologue: chunk-0 stage + chunk-0 words (drained by first barrier)
    stage(0, 0);
    WVLOAD(wa0, wa1, wa2, wa3, 0);

    // 2-chunk unrolled ping-pong; all buffer selects are compile-time.
    #pragma unroll
    for (int cc = 0; cc < NCHUNK; cc += 2) {
        __syncthreads();   // drains stage(cc)+wa(cc), issued one phase ago
        if (cc + 1 < NCHUNK) {
            stage(1, cc + 1);
            WVLOAD(wb0, wb1, wb2, wb3, cc + 1);
        }
        __builtin_amdgcn_sched_barrier(0);   // keep issue burst at phase top
        COMPUTE(0, wa0, wa1, wa2, wa3);      // zero vmem waits

        __syncthreads();   // drains stage(cc+1)+wb(cc+1)
        if (cc + 2 < NCHUNK) {
            stage(0, cc + 2);
            WVLOAD(wa0, wa1, wa2, wa3, cc + 2);
        }
        __builtin_amdgcn_sched_barrier(0);
        COMPUTE(1, wb0, wb1, wb2, wb3);
    }

    // epilogue: DPP wave-sum each acc, max over regions, lane 63 stores.
    #pragma unroll
    for (int w = 0; w < WPW; ++w) {
        float m = -INFINITY;
        #pragma unroll
        for (int r = 0; r < NREG; ++r)
            m = fmaxf(m, wave_sum64(acc[r][w]));
        if (lane == 63) out[(size_t)b * LWORDS + l0 + w] = m;
    }
}

extern "C" void kernel_launch(void* const* d_in, const int* in_sizes, int n_in,
                              void* d_out, int out_size, void* d_ws, size_t ws_size,
                              hipStream_t stream) {
    const float* in0 = (const float*)d_in[0];   // (B*20, D)
    const float* in1 = (const float*)d_in[1];   // (B, L, D)
    float* out = (float*)d_out;                  // (B, 1, L)

    const int grid = 64 * (LWORDS / WORDS_PER_BLOCK);   // 64 * 64 = 4096
    score_max_kernel<<<grid, TPB, 0, stream>>>(in0, in1, out);
}